// Round 9
// baseline (273.815 us; speedup 1.0000x reference)
//
#include <hip/hip_runtime.h>
#include <stdint.h>

// GCN 2-hop, R9: block-level fusion of aggregation+GEMM per layer.
//   memset -> k_prep -> k_scan -> k_fill
//          -> k_layer1: per 16-row block: [4 waves gather S@x -> LDS As]
//                       + R8-proven GEMM: h1 = LN(relu(As@W1+b1)+x@Wres+bres)
//          -> k_layer2: per 16-row block: [gather S@h1 -> LDS As]
//                       + R8-proven GEMM: out = LN(As@W2 + b2 + h1)
// vs R8: deletes Sx/Sh1 global round-trips + 2 dispatches. vs R7 (which
// diverged post-timing): 4-wave blocks, R8's GEMM/LN phase byte-identical,
// R8's agg inner loop with only the destination swapped to LDS.

constexpr int DIN = 128;
constexpr int DH  = 256;
#define LN_EPS 1e-5f

typedef __attribute__((ext_vector_type(8))) short bf16x8;  // 16 B
typedef __attribute__((ext_vector_type(4))) short bf16x4;  // 8 B
typedef __attribute__((ext_vector_type(4))) float f32x4;

__device__ __forceinline__ short f2bf(float f) {
  union { float f; unsigned u; } v; v.f = f;
  unsigned r = v.u + 0x7fffu + ((v.u >> 16) & 1u);  // RNE
  return (short)(r >> 16);
}
__device__ __forceinline__ float bf2f(short b) {
  union { unsigned u; float f; } v; v.u = ((unsigned)(unsigned short)b) << 16;
  return v.f;
}

// edge_index may be int32 (JAX x64 off) or int64: sample odd 32-bit words of
// the src half; all-zero <=> int64. Call with the wave converged.
__device__ __forceinline__ int probe_m64(const unsigned* ei, int E) {
  int lane = threadIdx.x & 63;
  long long stride = (E >= 64) ? (E / 64) : 1;
  long long li = (long long)lane * stride;
  if (li >= E) li = 0;
  unsigned v = ei[2 * li + 1];
  return __ballot(v != 0u) == 0ull;
}

__device__ __forceinline__ int eidx(const void* ei, long long e, int m64) {
  return m64 ? (int)((const long long*)ei)[e] : ((const int*)ei)[e];
}

// ------- prep: x->bf16 + 3 weight transposes + edge accumulation -------
// deg/cnt memset-0 before this kernel; self-loop +1 added in k_scan.

__global__ __launch_bounds__(256) void k_prep(const float* __restrict__ x,
                                              short* __restrict__ xb,
                                              const float* __restrict__ W1,
                                              const float* __restrict__ Wres,
                                              const float* __restrict__ W2,
                                              short* __restrict__ W1t,
                                              short* __restrict__ Wrt,
                                              short* __restrict__ W2t,
                                              const void* ei,
                                              const float* __restrict__ ew,
                                              float* deg, int* cnt,
                                              int N, int E) {
  const int NXV = N * DIN / 8;
  const int NW  = DIN * DH;              // 32768
  const int NW2 = DH * DH;               // 65536
  int idx = blockIdx.x * 256 + threadIdx.x;
  if (idx < NXV) {
    f32x4 a = ((const f32x4*)x)[idx * 2];
    f32x4 b = ((const f32x4*)x)[idx * 2 + 1];
    bf16x8 o;
    o[0] = f2bf(a[0]); o[1] = f2bf(a[1]); o[2] = f2bf(a[2]); o[3] = f2bf(a[3]);
    o[4] = f2bf(b[0]); o[5] = f2bf(b[1]); o[6] = f2bf(b[2]); o[7] = f2bf(b[3]);
    ((bf16x8*)xb)[idx] = o;
    return;
  }
  idx -= NXV;
  if (idx < NW) {
    int n = idx / DIN, k = idx % DIN;
    W1t[idx] = f2bf(W1[k * DH + n]);
    return;
  }
  idx -= NW;
  if (idx < NW) {
    int n = idx / DIN, k = idx % DIN;
    Wrt[idx] = f2bf(Wres[k * DH + n]);
    return;
  }
  idx -= NW;
  if (idx < NW2) {
    int n = idx / DH, k = idx % DH;
    W2t[idx] = f2bf(W2[k * DH + n]);
    return;
  }
  idx -= NW2;
  int m64 = probe_m64((const unsigned*)ei, E);
  if (idx < E) {
    int d = eidx(ei, (long long)E + idx, m64);
    atomicAdd(&deg[d], ew[idx]);
    atomicAdd(&cnt[d], 1);
  }
}

// ---- single block, single pass: dinv=rsqrt(1+deg); scan cnt->rowptr/cursor --

__global__ __launch_bounds__(1024) void k_scan(const int* __restrict__ cnt,
                                               float* deg, int* rowptr,
                                               int* cursor, int n) {
  for (int i = threadIdx.x; i < n; i += 1024) deg[i] = rsqrtf(1.0f + deg[i]);

  constexpr int MAXI = 32;
  int items = (n + 1023) / 1024;         // 20 for N=20000
  int tid = threadIdx.x, lane = tid & 63, wv = tid >> 6;
  int base = tid * items;
  int v[MAXI];
  int tot = 0;
#pragma unroll 4
  for (int j = 0; j < items; ++j) {
    int i = base + j;
    v[j] = (i < n) ? cnt[i] : 0;
    tot += v[j];
  }
  int sc = tot;
#pragma unroll
  for (int off = 1; off < 64; off <<= 1) {
    int t = __shfl_up(sc, off, 64);
    if (lane >= off) sc += t;
  }
  __shared__ int wsum[16];
  if (lane == 63) wsum[wv] = sc;
  __syncthreads();
  if (wv == 0 && lane < 16) {
    int s = wsum[lane];
#pragma unroll
    for (int off = 1; off < 16; off <<= 1) {
      int t = __shfl_up(s, off, 64);
      if (lane >= off) s += t;
    }
    wsum[lane] = s;
  }
  __syncthreads();
  int prefix = (sc - tot) + ((wv > 0) ? wsum[wv - 1] : 0);
  if (tid == 0) { rowptr[0] = 0; cursor[0] = 0; }
  int run = prefix;
#pragma unroll 4
  for (int j = 0; j < items; ++j) {
    int i = base + j;
    run += v[j];
    if (i < n) { rowptr[i + 1] = run; cursor[i + 1] = run; }
  }
}

// ---------------- CSR fill ----------------

__global__ __launch_bounds__(256) void k_fill(const void* ei,
                                              const float* __restrict__ w,
                                              const float* __restrict__ dinv,
                                              int* cursor, int* srcs,
                                              float* norms, int E) {
  int m64 = probe_m64((const unsigned*)ei, E);
  int e = blockIdx.x * 256 + threadIdx.x;
  if (e >= E) return;
  int s = eidx(ei, e, m64);
  int d = eidx(ei, (long long)E + e, m64);
  int p = atomicAdd(&cursor[d], 1);
  srcs[p] = s;
  norms[p] = dinv[s] * w[e] * dinv[d];
}

// ------- layer 1 fused: gather S@x (4 nodes/wave -> LDS) + GEMM + LN -------
// h1 = LN(relu((S@x)@W1+b1) + x@Wres + bres)

__global__ __launch_bounds__(256) void k_layer1(
    const short* __restrict__ xb, const short* __restrict__ W1t,
    const short* __restrict__ Wrt, const float* __restrict__ b1,
    const float* __restrict__ bres, const float* __restrict__ g1,
    const float* __restrict__ be1, const int* __restrict__ rowptr,
    const int* __restrict__ srcs, const float* __restrict__ norms,
    const float* __restrict__ dinv, short* __restrict__ h1b, int M) {
  __shared__ short As[16][DIN + 8];     // 272B row stride = 17x16B: balanced
  __shared__ short Xs[16][DIN + 8];
  __shared__ float red1[4][16], red2[4][16];
  int tid = threadIdx.x;
  int wv = tid >> 6, lane = tid & 63;
  int lr = lane & 15, lg = lane >> 4;
  int bm = blockIdx.x * 16;

  {  // stage Xs tile (R8 pattern)
    int row = tid >> 4, ch = tid & 15;
    int gr = min(bm + row, M - 1);
    *(bf16x8*)(&Xs[row][ch * 8]) = *(const bf16x8*)(xb + (long long)gr * DIN + ch * 8);
  }

  // gather: each wave aggregates 4 nodes (R8 agg128 body, dest = LDS)
  {
    int h = lane >> 5;
    int c = (lane & 31) * 4;
#pragma unroll
    for (int rr = 0; rr < 4; ++rr) {
      int r = wv * 4 + rr;
      int i = min(bm + r, M - 1);
      float a0 = 0.f, a1 = 0.f, a2 = 0.f, a3 = 0.f;
      int e = rowptr[i] + h, end = rowptr[i + 1];
      for (; e + 6 < end; e += 8) {
        int s0 = srcs[e], s1 = srcs[e + 2], s2 = srcs[e + 4], s3 = srcs[e + 6];
        float w0 = norms[e], w1 = norms[e + 2], w2 = norms[e + 4], w3 = norms[e + 6];
        bf16x4 v0 = *(const bf16x4*)(xb + (long long)s0 * DIN + c);
        bf16x4 v1 = *(const bf16x4*)(xb + (long long)s1 * DIN + c);
        bf16x4 v2 = *(const bf16x4*)(xb + (long long)s2 * DIN + c);
        bf16x4 v3 = *(const bf16x4*)(xb + (long long)s3 * DIN + c);
        a0 += w0 * bf2f(v0[0]) + w1 * bf2f(v1[0]) + w2 * bf2f(v2[0]) + w3 * bf2f(v3[0]);
        a1 += w0 * bf2f(v0[1]) + w1 * bf2f(v1[1]) + w2 * bf2f(v2[1]) + w3 * bf2f(v3[1]);
        a2 += w0 * bf2f(v0[2]) + w1 * bf2f(v1[2]) + w2 * bf2f(v2[2]) + w3 * bf2f(v3[2]);
        a3 += w0 * bf2f(v0[3]) + w1 * bf2f(v1[3]) + w2 * bf2f(v2[3]) + w3 * bf2f(v3[3]);
      }
      for (; e < end; e += 2) {
        int s = srcs[e];
        float w = norms[e];
        bf16x4 v = *(const bf16x4*)(xb + (long long)s * DIN + c);
        a0 += w * bf2f(v[0]); a1 += w * bf2f(v[1]);
        a2 += w * bf2f(v[2]); a3 += w * bf2f(v[3]);
      }
      a0 += __shfl_xor(a0, 32, 64); a1 += __shfl_xor(a1, 32, 64);
      a2 += __shfl_xor(a2, 32, 64); a3 += __shfl_xor(a3, 32, 64);
      if (h == 0) {
        float sw = dinv[i] * dinv[i];
        bf16x4 sv = *(const bf16x4*)(xb + (long long)i * DIN + c);
        bf16x4 o;
        o[0] = f2bf(a0 + sw * bf2f(sv[0]));
        o[1] = f2bf(a1 + sw * bf2f(sv[1]));
        o[2] = f2bf(a2 + sw * bf2f(sv[2]));
        o[3] = f2bf(a3 + sw * bf2f(sv[3]));
        *(bf16x4*)(&As[r][c]) = o;
      }
    }
  }
  __syncthreads();

  // ---- GEMM + LN (byte-identical to R8 k_gemm_ln1) ----
  f32x4 acc[4] = {};
#pragma unroll
  for (int ks = 0; ks < 4; ++ks) {
    bf16x8 a = *(const bf16x8*)(&As[lr][ks * 32 + lg * 8]);
#pragma unroll
    for (int ni = 0; ni < 4; ++ni) {
      int col = (wv * 4 + ni) * 16 + lr;
      bf16x8 b = *(const bf16x8*)(W1t + col * DIN + ks * 32 + lg * 8);
      acc[ni] = __builtin_amdgcn_mfma_f32_16x16x32_bf16(a, b, acc[ni], 0, 0, 0);
    }
  }
#pragma unroll
  for (int ni = 0; ni < 4; ++ni) {
    int col = (wv * 4 + ni) * 16 + lr;
    float bb = b1[col], br = bres[col];
#pragma unroll
    for (int j = 0; j < 4; ++j)
      acc[ni][j] = fmaxf(acc[ni][j] + bb, 0.f) + br;
  }
#pragma unroll
  for (int ks = 0; ks < 4; ++ks) {
    bf16x8 a = *(const bf16x8*)(&Xs[lr][ks * 32 + lg * 8]);
#pragma unroll
    for (int ni = 0; ni < 4; ++ni) {
      int col = (wv * 4 + ni) * 16 + lr;
      bf16x8 b = *(const bf16x8*)(Wrt + col * DIN + ks * 32 + lg * 8);
      acc[ni] = __builtin_amdgcn_mfma_f32_16x16x32_bf16(a, b, acc[ni], 0, 0, 0);
    }
  }
#pragma unroll
  for (int j = 0; j < 4; ++j) {
    float s1 = acc[0][j] + acc[1][j] + acc[2][j] + acc[3][j];
    float s2 = acc[0][j] * acc[0][j] + acc[1][j] * acc[1][j] +
               acc[2][j] * acc[2][j] + acc[3][j] * acc[3][j];
#pragma unroll
    for (int m = 1; m < 16; m <<= 1) {
      s1 += __shfl_xor(s1, m, 64);
      s2 += __shfl_xor(s2, m, 64);
    }
    if (lr == 0) { red1[wv][lg * 4 + j] = s1; red2[wv][lg * 4 + j] = s2; }
  }
  __syncthreads();
#pragma unroll
  for (int j = 0; j < 4; ++j) {
    int row = lg * 4 + j;
    float s1 = red1[0][row] + red1[1][row] + red1[2][row] + red1[3][row];
    float s2 = red2[0][row] + red2[1][row] + red2[2][row] + red2[3][row];
    float mu = s1 * (1.f / 256.f);
    float rs = rsqrtf(s2 * (1.f / 256.f) - mu * mu + LN_EPS);
    int r = bm + row;
    if (r < M) {
#pragma unroll
      for (int ni = 0; ni < 4; ++ni) {
        int col = (wv * 4 + ni) * 16 + lr;
        float y = (acc[ni][j] - mu) * rs * g1[col] + be1[col];
        h1b[(long long)r * DH + col] = f2bf(y);
      }
    }
  }
}

// ------- layer 2 fused: gather S@h1 (4 nodes/wave -> LDS) + GEMM + LN ------
// out = LN((S@h1)@W2 + b2 + h1)  (f32 out)

__global__ __launch_bounds__(256) void k_layer2(
    const short* __restrict__ h1b, const short* __restrict__ W2t,
    const float* __restrict__ b2, const float* __restrict__ g2,
    const float* __restrict__ be2, const int* __restrict__ rowptr,
    const int* __restrict__ srcs, const float* __restrict__ norms,
    const float* __restrict__ dinv, float* __restrict__ out, int M) {
  __shared__ short As[16][DH + 8];      // 528B row stride = 33x16B: balanced
  __shared__ short Hs[16][DH + 8];
  __shared__ float red1[4][16], red2[4][16];
  int tid = threadIdx.x;
  int wv = tid >> 6, lane = tid & 63;
  int lr = lane & 15, lg = lane >> 4;
  int bm = blockIdx.x * 16;

  {  // stage Hs residual tile (R8 pattern)
#pragma unroll
    for (int q = 0; q < 2; ++q) {
      int cidx = q * 256 + tid;
      int row = cidx >> 5, ch = cidx & 31;
      int gr = min(bm + row, M - 1);
      *(bf16x8*)(&Hs[row][ch * 8]) = *(const bf16x8*)(h1b + (long long)gr * DH + ch * 8);
    }
  }

  // gather: each wave aggregates 4 nodes (R8 agg256 body, dest = LDS)
  {
    int h = lane >> 5;
    int c = (lane & 31) * 8;
#pragma unroll
    for (int rr = 0; rr < 4; ++rr) {
      int r = wv * 4 + rr;
      int i = min(bm + r, M - 1);
      float acc[8];
#pragma unroll
      for (int k = 0; k < 8; ++k) acc[k] = 0.f;
      int e = rowptr[i] + h, end = rowptr[i + 1];
      for (; e + 6 < end; e += 8) {
        int s0 = srcs[e], s1 = srcs[e + 2], s2 = srcs[e + 4], s3 = srcs[e + 6];
        float w0 = norms[e], w1 = norms[e + 2], w2 = norms[e + 4], w3 = norms[e + 6];
        bf16x8 v0 = *(const bf16x8*)(h1b + (long long)s0 * DH + c);
        bf16x8 v1 = *(const bf16x8*)(h1b + (long long)s1 * DH + c);
        bf16x8 v2 = *(const bf16x8*)(h1b + (long long)s2 * DH + c);
        bf16x8 v3 = *(const bf16x8*)(h1b + (long long)s3 * DH + c);
#pragma unroll
        for (int k = 0; k < 8; ++k)
          acc[k] += w0 * bf2f(v0[k]) + w1 * bf2f(v1[k]) +
                    w2 * bf2f(v2[k]) + w3 * bf2f(v3[k]);
      }
      for (; e < end; e += 2) {
        int s = srcs[e];
        float w = norms[e];
        bf16x8 v = *(const bf16x8*)(h1b + (long long)s * DH + c);
#pragma unroll
        for (int k = 0; k < 8; ++k) acc[k] += w * bf2f(v[k]);
      }
#pragma unroll
      for (int k = 0; k < 8; ++k) acc[k] += __shfl_xor(acc[k], 32, 64);
      if (h == 0) {
        float sw = dinv[i] * dinv[i];
        bf16x8 sv = *(const bf16x8*)(h1b + (long long)i * DH + c);
        bf16x8 o;
#pragma unroll
        for (int k = 0; k < 8; ++k) o[k] = f2bf(acc[k] + sw * bf2f(sv[k]));
        *(bf16x8*)(&As[r][c]) = o;
      }
    }
  }
  __syncthreads();

  // ---- GEMM + residual + LN (byte-identical to R8 k_gemm_ln2) ----
  f32x4 acc[4] = {};
#pragma unroll
  for (int ks = 0; ks < 8; ++ks) {
    bf16x8 a = *(const bf16x8*)(&As[lr][ks * 32 + lg * 8]);
#pragma unroll
    for (int ni = 0; ni < 4; ++ni) {
      int col = (wv * 4 + ni) * 16 + lr;
      bf16x8 b = *(const bf16x8*)(W2t + col * DH + ks * 32 + lg * 8);
      acc[ni] = __builtin_amdgcn_mfma_f32_16x16x32_bf16(a, b, acc[ni], 0, 0, 0);
    }
  }
#pragma unroll
  for (int j = 0; j < 4; ++j) {
    int row = lg * 4 + j;
#pragma unroll
    for (int ni = 0; ni < 4; ++ni) {
      int col = (wv * 4 + ni) * 16 + lr;
      acc[ni][j] += b2[col] + bf2f(Hs[row][col]);
    }
  }
#pragma unroll
  for (int j = 0; j < 4; ++j) {
    float s1 = acc[0][j] + acc[1][j] + acc[2][j] + acc[3][j];
    float s2 = acc[0][j] * acc[0][j] + acc[1][j] * acc[1][j] +
               acc[2][j] * acc[2][j] + acc[3][j] * acc[3][j];
#pragma unroll
    for (int m = 1; m < 16; m <<= 1) {
      s1 += __shfl_xor(s1, m, 64);
      s2 += __shfl_xor(s2, m, 64);
    }
    if (lr == 0) { red1[wv][lg * 4 + j] = s1; red2[wv][lg * 4 + j] = s2; }
  }
  __syncthreads();
#pragma unroll
  for (int j = 0; j < 4; ++j) {
    int row = lg * 4 + j;
    float s1 = red1[0][row] + red1[1][row] + red1[2][row] + red1[3][row];
    float s2 = red2[0][row] + red2[1][row] + red2[2][row] + red2[3][row];
    float mu = s1 * (1.f / 256.f);
    float rs = rsqrtf(s2 * (1.f / 256.f) - mu * mu + LN_EPS);
    int r = bm + row;
    if (r < M) {
#pragma unroll
      for (int ni = 0; ni < 4; ++ni) {
        int col = (wv * 4 + ni) * 16 + lr;
        out[(long long)r * DH + col] = (acc[ni][j] - mu) * rs * g2[col] + be2[col];
      }
    }
  }
}

// ---------------- launcher ----------------

extern "C" void kernel_launch(void* const* d_in, const int* in_sizes, int n_in,
                              void* d_out, int out_size, void* d_ws,
                              size_t ws_size, hipStream_t stream) {
  const float* x    = (const float*)d_in[0];
  const void*  ei   = d_in[1];
  const float* ew   = (const float*)d_in[2];
  const float* W1   = (const float*)d_in[3];
  const float* b1   = (const float*)d_in[4];
  const float* W2   = (const float*)d_in[5];
  const float* b2   = (const float*)d_in[6];
  const float* Wres = (const float*)d_in[7];
  const float* bres = (const float*)d_in[8];
  const float* g1   = (const float*)d_in[9];
  const float* be1  = (const float*)d_in[10];
  const float* g2   = (const float*)d_in[11];
  const float* be2  = (const float*)d_in[12];

  const int N = in_sizes[0] / DIN;
  const int E = in_sizes[2];

  char* ws = (char*)d_ws;
  auto alloc = [&](size_t bytes) -> char* {
    char* p = ws;
    ws += (bytes + 255) & ~(size_t)255;
    return p;
  };
  short* xb     = (short*)alloc((size_t)N * DIN * 2);
  short* W1t    = (short*)alloc((size_t)DIN * DH * 2);
  short* Wrt    = (short*)alloc((size_t)DIN * DH * 2);
  short* W2t    = (short*)alloc((size_t)DH * DH * 2);
  short* h1b    = (short*)alloc((size_t)N * DH * 2);
  int*   cnt    = (int*)alloc((size_t)N * 8);   // cnt[N] + deg[N]
  float* deg    = (float*)(cnt + N);            // becomes dinv in k_scan
  int*   rowptr = (int*)alloc((size_t)(N + 1) * 4);
  int*   cursor = (int*)alloc((size_t)(N + 1) * 4);
  int*   srcs   = (int*)alloc((size_t)E * 4);
  float* norms  = (float*)alloc((size_t)E * 4);

  hipMemsetAsync(cnt, 0, (size_t)N * 8, stream);

  int prep_items = N * DIN / 8 + 2 * DIN * DH + DH * DH + E;
  k_prep<<<(prep_items + 255) / 256, 256, 0, stream>>>(
      x, xb, W1, Wres, W2, W1t, Wrt, W2t, ei, ew, deg, cnt, N, E);
  k_scan<<<1, 1024, 0, stream>>>(cnt, deg, rowptr, cursor, N);
  k_fill<<<(E + 255) / 256, 256, 0, stream>>>(ei, ew, deg, cursor, srcs, norms, E);

  const int NB = (N + 15) / 16;          // 1250
  k_layer1<<<NB, 256, 0, stream>>>(xb, W1t, Wrt, b1, bres, g1, be1, rowptr,
                                   srcs, norms, deg, h1b, N);
  k_layer2<<<NB, 256, 0, stream>>>(h1b, W2t, b2, g2, be2, rowptr, srcs, norms,
                                   deg, (float*)d_out, N);
}